// Round 2
// baseline (4185.320 us; speedup 1.0000x reference)
//
#include <hip/hip_runtime.h>

#define Bdim 64
#define Tdim 512
#define Idim 512
#define Hdim 512
#define CLIPV 10.0f

typedef __attribute__((ext_vector_type(4))) float f32x4;
typedef __attribute__((ext_vector_type(8))) short bf16x8;

__device__ __forceinline__ ushort f2bf(float f) {
    unsigned u = __builtin_bit_cast(unsigned, f);
    u += 0x7fffu + ((u >> 16) & 1u);   // round-to-nearest-even
    return (ushort)(u >> 16);
}
__device__ __forceinline__ float bf2f(ushort h) {
    return __builtin_bit_cast(float, (unsigned)h << 16);
}
__device__ __forceinline__ void split_bf(float f, ushort& h, ushort& l) {
    h = f2bf(f);
    l = f2bf(f - bf2f(h));   // residual exact in f32; second rounding ~2^-18 rel
}

// ---- cast + transpose W into hi/lo bf16: Wt[n][k] = split(W[k][n]) ----
__global__ __launch_bounds__(256) void transpose_w_kernel(const float* __restrict__ w,
                                                          ushort* __restrict__ wth,
                                                          ushort* __restrict__ wtl) {
    int idx = blockIdx.x * 256 + threadIdx.x;   // 512*512 total
    int k = idx >> 9, n = idx & 511;
    ushort h, l;
    split_bf(w[idx], h, l);
    wth[n * Idim + k] = h;
    wtl[n * Idim + k] = l;
}

// ---- phase 1: pre = x @ W + bias via bf16x3 MFMA (hi*hi + hi*lo + lo*hi) ----
#define BM 128
#define BN 128
#define BK 32
__global__ __launch_bounds__(256) void gemm_xw(
    const float* __restrict__ A,     // [M,K] f32 (x)
    const ushort* __restrict__ Bth,  // [N,K] bf16 hi (W^T)
    const ushort* __restrict__ Btl,  // [N,K] bf16 lo
    const float* __restrict__ bias,  // [N]
    float* __restrict__ C,           // [M,N] f32
    int M, int N, int K)
{
    __shared__ ushort AsH[BM][BK];
    __shared__ ushort AsL[BM][BK];
    __shared__ ushort BsH[BN][BK];
    __shared__ ushort BsL[BN][BK];
    int bm = blockIdx.x, bn = blockIdx.y;
    int tid = threadIdx.x;
    int wave = tid >> 6, lane = tid & 63;
    int wr = wave >> 1, wc = wave & 1;          // 2x2 waves, each 64x64
    f32x4 acc[4][4] = {};
    const int row0 = bm * BM, col0 = bn * BN;
    const int sr = tid >> 1;                    // 0..127
    const int sc = (tid & 1) * 16;              // 0 / 16

    for (int kt = 0; kt < K; kt += BK) {
        // A: load 16 f32, split hi/lo on the fly
        const float* gA = A + (size_t)(row0 + sr) * K + kt + sc;
        #pragma unroll
        for (int q = 0; q < 4; ++q) {
            float4 v = *(const float4*)(gA + q * 4);
            ushort4 h4, l4;
            split_bf(v.x, h4.x, l4.x);
            split_bf(v.y, h4.y, l4.y);
            split_bf(v.z, h4.z, l4.z);
            split_bf(v.w, h4.w, l4.w);
            *(ushort4*)&AsH[sr][sc + q * 4] = h4;
            *(ushort4*)&AsL[sr][sc + q * 4] = l4;
        }
        // B: pre-split bf16, straight vector copies
        const int4* gBh = (const int4*)(Bth + (size_t)(col0 + sr) * K + kt + sc);
        *(int4*)&BsH[sr][sc]     = gBh[0];
        *(int4*)&BsH[sr][sc + 8] = gBh[1];
        const int4* gBl = (const int4*)(Btl + (size_t)(col0 + sr) * K + kt + sc);
        *(int4*)&BsL[sr][sc]     = gBl[0];
        *(int4*)&BsL[sr][sc + 8] = gBl[1];
        __syncthreads();

        const int r = lane & 15, kg = lane >> 4;   // k-chunk = kg*8
        bf16x8 ah[4], al[4], bh[4], bl[4];
        #pragma unroll
        for (int m = 0; m < 4; ++m) {
            ah[m] = *(const bf16x8*)&AsH[wr * 64 + m * 16 + r][kg * 8];
            al[m] = *(const bf16x8*)&AsL[wr * 64 + m * 16 + r][kg * 8];
        }
        #pragma unroll
        for (int n = 0; n < 4; ++n) {
            bh[n] = *(const bf16x8*)&BsH[wc * 64 + n * 16 + r][kg * 8];
            bl[n] = *(const bf16x8*)&BsL[wc * 64 + n * 16 + r][kg * 8];
        }
        #pragma unroll
        for (int m = 0; m < 4; ++m)
            #pragma unroll
            for (int n = 0; n < 4; ++n) {
                acc[m][n] = __builtin_amdgcn_mfma_f32_16x16x32_bf16(ah[m], bh[n], acc[m][n], 0, 0, 0);
                acc[m][n] = __builtin_amdgcn_mfma_f32_16x16x32_bf16(ah[m], bl[n], acc[m][n], 0, 0, 0);
                acc[m][n] = __builtin_amdgcn_mfma_f32_16x16x32_bf16(al[m], bh[n], acc[m][n], 0, 0, 0);
            }
        __syncthreads();
    }

    const int cl = lane & 15, rg = lane >> 4;
    #pragma unroll
    for (int n = 0; n < 4; ++n) {
        int gc = col0 + wc * 64 + n * 16 + cl;
        float bv = bias[gc];
        #pragma unroll
        for (int m = 0; m < 4; ++m) {
            int gr = row0 + wr * 64 + m * 16 + rg * 4;
            #pragma unroll
            for (int r2 = 0; r2 < 4; ++r2)
                C[(size_t)(gr + r2) * N + gc] = acc[m][n][r2] + bv;
        }
    }
}

// ---- phase 2: sequential recurrence. One WG per batch row; h in LDS; stream R from L2.
__global__ __launch_bounds__(256) void rnn_kernel(
    const float* __restrict__ Rw,   // [H,H] f32
    float* __restrict__ out,        // [B,T,H] f32 (pre -> h in place)
    float* __restrict__ hlast,      // [B,H]
    const float* __restrict__ h0)   // [B,H]
{
    const int b = blockIdx.x;
    const int tid = threadIdx.x;
    const int c0 = (tid & 127) * 4;     // 4 output columns
    const int kh = tid >> 7;            // k-half: 0 -> k 0..255, 1 -> k 256..511
    __shared__ float h[Hdim];
    __shared__ float red[Hdim];

    for (int j = tid; j < Hdim; j += 256) h[j] = h0[b * Hdim + j];
    __syncthreads();

    float* orow = out + (size_t)b * Tdim * Hdim;
    const float* Rbase = Rw + (size_t)(kh * 256) * Hdim + c0;

    for (int t = 0; t < Tdim; ++t, orow += Hdim) {
        float a0 = 0.f, a1 = 0.f, a2 = 0.f, a3 = 0.f;
        #pragma unroll 2
        for (int kk = 0; kk < 256; kk += 4) {
            f32x4 hv = *(const f32x4*)&h[kh * 256 + kk];
            const float* rp = Rbase + (size_t)kk * Hdim;
            float4 r0 = *(const float4*)(rp);
            float4 r1 = *(const float4*)(rp + Hdim);
            float4 r2 = *(const float4*)(rp + 2 * Hdim);
            float4 r3 = *(const float4*)(rp + 3 * Hdim);
            a0 += hv.x * r0.x; a1 += hv.x * r0.y; a2 += hv.x * r0.z; a3 += hv.x * r0.w;
            a0 += hv.y * r1.x; a1 += hv.y * r1.y; a2 += hv.y * r1.z; a3 += hv.y * r1.w;
            a0 += hv.z * r2.x; a1 += hv.z * r2.y; a2 += hv.z * r2.z; a3 += hv.z * r2.w;
            a0 += hv.w * r3.x; a1 += hv.w * r3.y; a2 += hv.w * r3.z; a3 += hv.w * r3.w;
        }
        if (kh) {
            red[c0] = a0; red[c0 + 1] = a1; red[c0 + 2] = a2; red[c0 + 3] = a3;
        }
        __syncthreads();
        if (!kh) {
            float4 pre = *(const float4*)(orow + c0);
            float g0 = a0 + red[c0]     + pre.x;
            float g1 = a1 + red[c0 + 1] + pre.y;
            float g2 = a2 + red[c0 + 2] + pre.z;
            float g3 = a3 + red[c0 + 3] + pre.w;
            g0 = fminf(fmaxf(g0, -CLIPV), CLIPV);
            g1 = fminf(fmaxf(g1, -CLIPV), CLIPV);
            g2 = fminf(fmaxf(g2, -CLIPV), CLIPV);
            g3 = fminf(fmaxf(g3, -CLIPV), CLIPV);
            float v0 = tanhf(g0), v1 = tanhf(g1), v2 = tanhf(g2), v3 = tanhf(g3);
            float4 hv_out = make_float4(v0, v1, v2, v3);
            *(float4*)(orow + c0) = hv_out;
            h[c0] = v0; h[c0 + 1] = v1; h[c0 + 2] = v2; h[c0 + 3] = v3;
        }
        __syncthreads();
    }
    for (int j = tid; j < Hdim; j += 256) hlast[b * Hdim + j] = h[j];
}

extern "C" void kernel_launch(void* const* d_in, const int* in_sizes, int n_in,
                              void* d_out, int out_size, void* d_ws, size_t ws_size,
                              hipStream_t stream) {
    const float* x    = (const float*)d_in[0];
    const float* W    = (const float*)d_in[1];
    const float* R    = (const float*)d_in[2];
    const float* bias = (const float*)d_in[3];
    const float* h0   = (const float*)d_in[4];
    float* out = (float*)d_out;

    ushort* wth = (ushort*)d_ws;                                  // 512 KB bf16 W^T hi
    ushort* wtl = wth + (size_t)Idim * Hdim;                      // 512 KB bf16 W^T lo

    transpose_w_kernel<<<(Idim * Hdim + 255) / 256, 256, 0, stream>>>(W, wth, wtl);

    dim3 gg(Bdim * Tdim / BM, Hdim / BN);
    gemm_xw<<<gg, 256, 0, stream>>>(x, wth, wtl, bias, out, Bdim * Tdim, Hdim, Idim);

    rnn_kernel<<<Bdim, 256, 0, stream>>>(R, out, out + (size_t)Bdim * Tdim * Hdim, h0);
}